// Round 10
// baseline (109.882 us; speedup 1.0000x reference)
//
#include <hip/hip_runtime.h>
#include <math.h>

#define BB   512
#define TT   256
#define EMBD 364
#define HS   64
#define KPAD 384
#define NC   192
#define XP   68      // fp32 LDS x-tile pitch: 68%32=4 -> conflict-free b128 frag reads

typedef __attribute__((ext_vector_type(8))) short short8_t;  // 8 bf16
typedef __attribute__((ext_vector_type(4))) float f32x4;

__device__ __forceinline__ ushort f2bf(float v) {
    union { float f; unsigned u; } c; c.f = v;
    unsigned b = c.u;
    return (ushort)((b + 0x7FFF + ((b >> 16) & 1)) >> 16);   // RNE
}
__device__ __forceinline__ ushort f2bfc(float v) {           // cheap round (A-frags only)
    union { float f; unsigned u; } c; c.f = v;
    return (ushort)((c.u + 0x8000u) >> 16);
}

// async global->LDS, 4B per lane: lane l writes LP + l*4
#define GLOAD_LDS4(GP, LP)                                                        \
    __builtin_amdgcn_global_load_lds(                                             \
        (const __attribute__((address_space(1))) void*)(const void*)(GP),         \
        (__attribute__((address_space(3))) void*)(void*)(LP), 4, 0, 0)

// ---------------- d_ws layout (bytes) ----------------
#define WTR_BYTES ((size_t)144 * 512 * 2)            // 147456 (B-frag-ordered W)
#define KQ_ELEMS  ((size_t)BB * TT * HS)             // 8388608
#define K_OFF_B   (WTR_BYTES)
#define Q_OFF_B   (K_OFF_B + KQ_ELEMS * 2)
#define VT_OFF_B  (Q_OFF_B + KQ_ELEMS * 2)

// ---------- kernel 0: W -> B-fragment-ordered bf16 WTr, k-part pre-scaled ----------
__global__ void prep_wtr(const float* __restrict__ Wk, const float* __restrict__ Wq,
                         const float* __restrict__ Wv, ushort* __restrict__ WTr)
{
    const int bid = blockIdx.x;          // 0..143 = jj*12 + t
    const int jj  = bid / 12;
    const int t   = bid % 12;
    const int l   = threadIdx.x;
    const int c   = jj * 16 + (l & 15);
    const float* Wp = (c < 64) ? Wk : (c < 128 ? Wq : Wv);
    const float s   = (c < 64) ? 0.125f : 1.0f;
    const int col   = c & 63;
    #pragma unroll
    for (int i = 0; i < 8; ++i) {
        int k = t * 32 + (l >> 4) * 8 + i;
        float v = (k < EMBD) ? Wp[(size_t)k * HS + col] * s : 0.f;
        WTr[((size_t)bid * 64 + l) * 8 + i] = f2bf(v);
    }
}

// ================= Kernel A: global_load_lds projection GEMM (m97-style) =================
// 2048 blocks x 256 thr (4 waves). Block: 64 M-rows, N=192 (wave w: 48 cols), K = 6x64.
// x staged fp32 via async global_load_lds (width 4, one instr per row, pitch-68 rows),
// double-buffered; conversion to bf16 at frag-read time. B direct from L2-resident WTr.
__global__ __launch_bounds__(256, 2) void proj_gemm(
    const float* __restrict__ x, const ushort* __restrict__ WTr,
    const float* __restrict__ bk_, const float* __restrict__ bq_,
    const float* __restrict__ bv_,
    ushort* __restrict__ Kg, ushort* __restrict__ Qg, ushort* __restrict__ Vt)
{
    const int blk = blockIdx.x;
    const int tid = threadIdx.x;
    const int l   = tid & 63;
    const int w   = tid >> 6;
    const int l15 = l & 15;
    const int lg  = l >> 4;

    __shared__ float xf[2][64 * XP];    // 2 x 17408 B

    const float* xb = x + (size_t)blk * 64 * EMBD;

    float bias3[3];
    #pragma unroll
    for (int j = 0; j < 3; ++j) {
        int c = w * 48 + j * 16 + l15;
        bias3[j] = (c < 64) ? bk_[c] * 0.125f : (c < 128 ? bq_[c - 64] : bv_[c - 128]);
    }

    f32x4 acc[4][3];
    #pragma unroll
    for (int mi = 0; mi < 4; ++mi)
        #pragma unroll
        for (int j = 0; j < 3; ++j) acc[mi][j] = (f32x4){0.f, 0.f, 0.f, 0.f};

    // ---- stage chunk kc into buf: wave w covers rows [w*16, w*16+16) ----
    auto STAGE = [&](int kc, int buf) {
        const int colv = kc * 64 + l;
        const int col  = (colv < EMBD) ? colv : 0;    // clamp; pads hit WTr zeros
        #pragma unroll
        for (int rr = 0; rr < 16; ++rr) {
            const int row = w * 16 + rr;
            const float* gp = xb + (size_t)row * EMBD + col;
            GLOAD_LDS4(gp, &xf[buf][row * XP]);
        }
    };

    // ---- compute chunk kc from buf ----
    auto COMPUTE = [&](int kc, int buf) {
        short8_t Bf[3][2];
        #pragma unroll
        for (int j = 0; j < 3; ++j)
            #pragma unroll
            for (int ks = 0; ks < 2; ++ks)
                Bf[j][ks] = *(const short8_t*)&WTr[(((size_t)(w * 3 + j) * 12 + kc * 2 + ks) * 64 + l) * 8];
        short8_t a[4][2];
        #pragma unroll
        for (int mi = 0; mi < 4; ++mi)
            #pragma unroll
            for (int ks = 0; ks < 2; ++ks) {
                const float* p = &xf[buf][(mi * 16 + l15) * XP + ks * 32 + lg * 8];
                float4 p0 = *(const float4*)p;
                float4 p1 = *(const float4*)(p + 4);
                union { short8_t s8; ushort us[8]; } pk;
                pk.us[0] = f2bfc(p0.x); pk.us[1] = f2bfc(p0.y);
                pk.us[2] = f2bfc(p0.z); pk.us[3] = f2bfc(p0.w);
                pk.us[4] = f2bfc(p1.x); pk.us[5] = f2bfc(p1.y);
                pk.us[6] = f2bfc(p1.z); pk.us[7] = f2bfc(p1.w);
                a[mi][ks] = pk.s8;
            }
        #pragma unroll
        for (int ks = 0; ks < 2; ++ks)
            #pragma unroll
            for (int mi = 0; mi < 4; ++mi)
                #pragma unroll
                for (int j = 0; j < 3; ++j)
                    acc[mi][j] = __builtin_amdgcn_mfma_f32_16x16x32_bf16(a[mi][ks], Bf[j][ks], acc[mi][j], 0, 0, 0);
    };

    STAGE(0, 0);
    __syncthreads();
    #pragma unroll
    for (int kc = 0; kc < 6; ++kc) {
        if (kc < 5) STAGE(kc + 1, (kc + 1) & 1);   // async; in flight during compute
        COMPUTE(kc, kc & 1);
        __syncthreads();                           // drains stage(kc+1) + lds reads
    }

    // ---- epilogue: +bias, K/Q row-major, V transposed per batch ----
    const int b   = blk >> 2;
    const int tl0 = (blk & 3) * 64;
    #pragma unroll
    for (int j = 0; j < 3; ++j) {
        const int c = w * 48 + j * 16 + l15;
        #pragma unroll
        for (int mi = 0; mi < 4; ++mi) {
            if (c < 64) {
                #pragma unroll
                for (int r = 0; r < 4; ++r) {
                    const size_t trow = (size_t)blk * 64 + mi * 16 + lg * 4 + r;
                    Kg[trow * HS + c] = f2bf(acc[mi][j][r] + bias3[j]);
                }
            } else if (c < 128) {
                #pragma unroll
                for (int r = 0; r < 4; ++r) {
                    const size_t trow = (size_t)blk * 64 + mi * 16 + lg * 4 + r;
                    Qg[trow * HS + (c - 64)] = f2bf(acc[mi][j][r] + bias3[j]);
                }
            } else {
                ushort4 pk;
                pk.x = f2bf(acc[mi][j][0] + bias3[j]);
                pk.y = f2bf(acc[mi][j][1] + bias3[j]);
                pk.z = f2bf(acc[mi][j][2] + bias3[j]);
                pk.w = f2bf(acc[mi][j][3] + bias3[j]);
                *(ushort4*)&Vt[((size_t)b * HS + (c - 128)) * TT + tl0 + mi * 16 + lg * 4] = pk;
            }
        }
    }
}

// ================= Kernel B: per-batch causal flash attention, no barriers =================
__global__ __launch_bounds__(512, 4) void attn_fused(
    const ushort* __restrict__ Kg, const ushort* __restrict__ Qg,
    const ushort* __restrict__ Vt, float* __restrict__ out)
{
    const int b   = blockIdx.x;
    const int tid = threadIdx.x;
    const int l   = tid & 63;
    const int w   = tid >> 6;
    const int l15 = l & 15;
    const int lg  = l >> 4;

    __shared__ ushort pb[8][16 * 40];
    ushort* pbw = pb[w];

    const ushort* Kb = Kg + (size_t)b * TT * HS;
    const ushort* Qb = Qg + (size_t)b * TT * HS;
    const ushort* Vb = Vt + (size_t)b * HS * TT;

    #pragma unroll
    for (int half = 0; half < 2; ++half) {
        const int rt = half ? (15 - w) : w;     // balanced causal work: 9 chunks/wave
        const int t0 = rt * 16;

        short8_t afr[2];
        afr[0] = *(const short8_t*)&Kb[(t0 + l15) * HS + lg * 8];
        afr[1] = *(const short8_t*)&Kb[(t0 + l15) * HS + 32 + lg * 8];

        float mr[4], lr[4];
        f32x4 o[4];
        #pragma unroll
        for (int r = 0; r < 4; ++r) { mr[r] = -INFINITY; lr[r] = 0.f; }
        #pragma unroll
        for (int nt = 0; nt < 4; ++nt) o[nt] = (f32x4){0.f, 0.f, 0.f, 0.f};

        const int jd = t0 >> 5;
        for (int j = 0; j <= jd; ++j) {
            const int sb = j * 32;
            f32x4 sacc[2];
            sacc[0] = (f32x4){0.f, 0.f, 0.f, 0.f};
            sacc[1] = (f32x4){0.f, 0.f, 0.f, 0.f};
            #pragma unroll
            for (int kk = 0; kk < 2; ++kk) {
                #pragma unroll
                for (int ct = 0; ct < 2; ++ct) {
                    short8_t bfr = *(const short8_t*)&Qb[(sb + ct * 16 + l15) * HS + kk * 32 + lg * 8];
                    sacc[ct] = __builtin_amdgcn_mfma_f32_16x16x32_bf16(afr[kk], bfr, sacc[ct], 0, 0, 0);
                }
            }
            #pragma unroll
            for (int ct = 0; ct < 2; ++ct) {
                int s = sb + ct * 16 + l15;
                #pragma unroll
                for (int r = 0; r < 4; ++r) {
                    int t = t0 + lg * 4 + r;
                    if (s > t) sacc[ct][r] = -INFINITY;
                }
            }
            float p0[4], p1[4], fsc[4];
            #pragma unroll
            for (int r = 0; r < 4; ++r) {
                float mx = fmaxf(sacc[0][r], sacc[1][r]);
                mx = fmaxf(mx, __shfl_xor(mx, 1));
                mx = fmaxf(mx, __shfl_xor(mx, 2));
                mx = fmaxf(mx, __shfl_xor(mx, 4));
                mx = fmaxf(mx, __shfl_xor(mx, 8));
                float nm = fmaxf(mr[r], mx);
                fsc[r] = __expf(mr[r] - nm);
                mr[r] = nm;
                p0[r] = __expf(sacc[0][r] - nm);
                p1[r] = __expf(sacc[1][r] - nm);
                float ps = p0[r] + p1[r];
                ps += __shfl_xor(ps, 1);
                ps += __shfl_xor(ps, 2);
                ps += __shfl_xor(ps, 4);
                ps += __shfl_xor(ps, 8);
                lr[r] = lr[r] * fsc[r] + ps;
            }
            #pragma unroll
            for (int nt = 0; nt < 4; ++nt)
                #pragma unroll
                for (int r = 0; r < 4; ++r) o[nt][r] *= fsc[r];
            #pragma unroll
            for (int r = 0; r < 4; ++r) {
                pbw[(lg * 4 + r) * 40 + l15]      = f2bf(p0[r]);
                pbw[(lg * 4 + r) * 40 + 16 + l15] = f2bf(p1[r]);
            }
            short8_t pa = *(const short8_t*)&pbw[l15 * 40 + lg * 8];
            #pragma unroll
            for (int nt = 0; nt < 4; ++nt) {
                short8_t bfr = *(const short8_t*)&Vb[(nt * 16 + l15) * TT + sb + lg * 8];
                o[nt] = __builtin_amdgcn_mfma_f32_16x16x32_bf16(pa, bfr, o[nt], 0, 0, 0);
            }
        }
        #pragma unroll
        for (int r = 0; r < 4; ++r) {
            float inv = 1.0f / lr[r];
            int t = t0 + lg * 4 + r;
            float* op = out + ((size_t)b * TT + t) * HS;
            #pragma unroll
            for (int nt = 0; nt < 4; ++nt)
                op[nt * 16 + l15] = o[nt][r] * inv;
        }
    }
}

extern "C" void kernel_launch(void* const* d_in, const int* in_sizes, int n_in,
                              void* d_out, int out_size, void* d_ws, size_t ws_size,
                              hipStream_t stream) {
    const float* x  = (const float*)d_in[0];
    const float* Wk = (const float*)d_in[1];
    const float* bk = (const float*)d_in[2];
    const float* Wq = (const float*)d_in[3];
    const float* bq = (const float*)d_in[4];
    const float* Wv = (const float*)d_in[5];
    const float* bv = (const float*)d_in[6];
    float* out = (float*)d_out;

    ushort* WTr = (ushort*)d_ws;
    ushort* Kg  = (ushort*)((char*)d_ws + K_OFF_B);
    ushort* Qg  = (ushort*)((char*)d_ws + Q_OFF_B);
    ushort* Vt  = (ushort*)((char*)d_ws + VT_OFF_B);

    prep_wtr<<<dim3(144), dim3(64), 0, stream>>>(Wk, Wq, Wv, WTr);
    proj_gemm<<<dim3(2048), dim3(256), 0, stream>>>(x, WTr, bk, bq, bv, Kg, Qg, Vt);
    attn_fused<<<dim3(BB), dim3(512), 0, stream>>>(Kg, Qg, Vt, out);
}

// Round 11
// 109.077 us; speedup vs baseline: 1.0074x; 1.0074x over previous
//
#include <hip/hip_runtime.h>
#include <math.h>

#define BB   512
#define TT   256
#define EMBD 364
#define HS   64
#define KPAD 384
#define NC   192
#define XP   68      // fp32 LDS x-tile pitch: 68%32=4 -> conflict-free b128 frag reads

typedef __attribute__((ext_vector_type(8))) short short8_t;  // 8 bf16
typedef __attribute__((ext_vector_type(4))) float f32x4;

__device__ __forceinline__ ushort f2bf(float v) {
    union { float f; unsigned u; } c; c.f = v;
    unsigned b = c.u;
    return (ushort)((b + 0x7FFF + ((b >> 16) & 1)) >> 16);   // RNE
}
__device__ __forceinline__ ushort f2bfc(float v) {           // cheap round (A-frags only)
    union { float f; unsigned u; } c; c.f = v;
    return (ushort)((c.u + 0x8000u) >> 16);
}

// async global->LDS, 4B per lane: lane l writes LP + l*4
#define GLOAD_LDS4(GP, LP)                                                        \
    __builtin_amdgcn_global_load_lds(                                             \
        (const __attribute__((address_space(1))) void*)(const void*)(GP),         \
        (__attribute__((address_space(3))) void*)(void*)(LP), 4, 0, 0)

// ---------------- d_ws layout (bytes) ----------------
#define WTR_BYTES ((size_t)144 * 512 * 2)            // 147456 (B-frag-ordered W)
#define KQ_ELEMS  ((size_t)BB * TT * HS)             // 8388608
#define K_OFF_B   (WTR_BYTES)
#define Q_OFF_B   (K_OFF_B + KQ_ELEMS * 2)
#define VT_OFF_B  (Q_OFF_B + KQ_ELEMS * 2)

// ---------- kernel 0: W -> B-fragment-ordered bf16 WTr, k-part pre-scaled ----------
__global__ void prep_wtr(const float* __restrict__ Wk, const float* __restrict__ Wq,
                         const float* __restrict__ Wv, ushort* __restrict__ WTr)
{
    const int bid = blockIdx.x;          // 0..143 = jj*12 + t
    const int jj  = bid / 12;
    const int t   = bid % 12;
    const int l   = threadIdx.x;
    const int c   = jj * 16 + (l & 15);
    const float* Wp = (c < 64) ? Wk : (c < 128 ? Wq : Wv);
    const float s   = (c < 64) ? 0.125f : 1.0f;
    const int col   = c & 63;
    #pragma unroll
    for (int i = 0; i < 8; ++i) {
        int k = t * 32 + (l >> 4) * 8 + i;
        float v = (k < EMBD) ? Wp[(size_t)k * HS + col] * s : 0.f;
        WTr[((size_t)bid * 64 + l) * 8 + i] = f2bf(v);
    }
}

// ================= Kernel A: global_load_lds projection GEMM (m97-style) =================
// 2048 blocks x 256 thr (4 waves). Block: 64 M-rows, N=192 (wave w: 48 cols), K = 6x64.
// x staged fp32 via async global_load_lds (width 4, one instr per row, pitch-68 rows),
// double-buffered; conversion to bf16 at frag-read time. B direct from L2-resident WTr.
__global__ __launch_bounds__(256, 2) void proj_gemm(
    const float* __restrict__ x, const ushort* __restrict__ WTr,
    const float* __restrict__ bk_, const float* __restrict__ bq_,
    const float* __restrict__ bv_,
    ushort* __restrict__ Kg, ushort* __restrict__ Qg, ushort* __restrict__ Vt)
{
    const int blk = blockIdx.x;
    const int tid = threadIdx.x;
    const int l   = tid & 63;
    const int w   = tid >> 6;
    const int l15 = l & 15;
    const int lg  = l >> 4;

    __shared__ float xf[2][64 * XP];    // 2 x 17408 B

    const float* xb = x + (size_t)blk * 64 * EMBD;

    float bias3[3];
    #pragma unroll
    for (int j = 0; j < 3; ++j) {
        int c = w * 48 + j * 16 + l15;
        bias3[j] = (c < 64) ? bk_[c] * 0.125f : (c < 128 ? bq_[c - 64] : bv_[c - 128]);
    }

    f32x4 acc[4][3];
    #pragma unroll
    for (int mi = 0; mi < 4; ++mi)
        #pragma unroll
        for (int j = 0; j < 3; ++j) acc[mi][j] = (f32x4){0.f, 0.f, 0.f, 0.f};

    // ---- stage chunk kc into buf: wave w covers rows [w*16, w*16+16) ----
    auto STAGE = [&](int kc, int buf) {
        const int colv = kc * 64 + l;
        const int col  = (colv < EMBD) ? colv : 0;    // clamp; pads hit WTr zeros
        #pragma unroll
        for (int rr = 0; rr < 16; ++rr) {
            const int row = w * 16 + rr;
            const float* gp = xb + (size_t)row * EMBD + col;
            GLOAD_LDS4(gp, &xf[buf][row * XP]);
        }
    };

    // ---- compute chunk kc from buf ----
    auto COMPUTE = [&](int kc, int buf) {
        short8_t Bf[3][2];
        #pragma unroll
        for (int j = 0; j < 3; ++j)
            #pragma unroll
            for (int ks = 0; ks < 2; ++ks)
                Bf[j][ks] = *(const short8_t*)&WTr[(((size_t)(w * 3 + j) * 12 + kc * 2 + ks) * 64 + l) * 8];
        short8_t a[4][2];
        #pragma unroll
        for (int mi = 0; mi < 4; ++mi)
            #pragma unroll
            for (int ks = 0; ks < 2; ++ks) {
                const float* p = &xf[buf][(mi * 16 + l15) * XP + ks * 32 + lg * 8];
                float4 p0 = *(const float4*)p;
                float4 p1 = *(const float4*)(p + 4);
                union { short8_t s8; ushort us[8]; } pk;
                pk.us[0] = f2bfc(p0.x); pk.us[1] = f2bfc(p0.y);
                pk.us[2] = f2bfc(p0.z); pk.us[3] = f2bfc(p0.w);
                pk.us[4] = f2bfc(p1.x); pk.us[5] = f2bfc(p1.y);
                pk.us[6] = f2bfc(p1.z); pk.us[7] = f2bfc(p1.w);
                a[mi][ks] = pk.s8;
            }
        #pragma unroll
        for (int ks = 0; ks < 2; ++ks)
            #pragma unroll
            for (int mi = 0; mi < 4; ++mi)
                #pragma unroll
                for (int j = 0; j < 3; ++j)
                    acc[mi][j] = __builtin_amdgcn_mfma_f32_16x16x32_bf16(a[mi][ks], Bf[j][ks], acc[mi][j], 0, 0, 0);
    };

    STAGE(0, 0);
    __syncthreads();
    #pragma unroll
    for (int kc = 0; kc < 6; ++kc) {
        if (kc < 5) STAGE(kc + 1, (kc + 1) & 1);   // async; in flight during compute
        COMPUTE(kc, kc & 1);
        __syncthreads();                           // drains stage(kc+1) + lds reads
    }

    // ---- epilogue: +bias, K/Q row-major, V transposed per batch ----
    const int b   = blk >> 2;
    const int tl0 = (blk & 3) * 64;
    #pragma unroll
    for (int j = 0; j < 3; ++j) {
        const int c = w * 48 + j * 16 + l15;
        #pragma unroll
        for (int mi = 0; mi < 4; ++mi) {
            if (c < 64) {
                #pragma unroll
                for (int r = 0; r < 4; ++r) {
                    const size_t trow = (size_t)blk * 64 + mi * 16 + lg * 4 + r;
                    Kg[trow * HS + c] = f2bf(acc[mi][j][r] + bias3[j]);
                }
            } else if (c < 128) {
                #pragma unroll
                for (int r = 0; r < 4; ++r) {
                    const size_t trow = (size_t)blk * 64 + mi * 16 + lg * 4 + r;
                    Qg[trow * HS + (c - 64)] = f2bf(acc[mi][j][r] + bias3[j]);
                }
            } else {
                ushort4 pk;
                pk.x = f2bf(acc[mi][j][0] + bias3[j]);
                pk.y = f2bf(acc[mi][j][1] + bias3[j]);
                pk.z = f2bf(acc[mi][j][2] + bias3[j]);
                pk.w = f2bf(acc[mi][j][3] + bias3[j]);
                *(ushort4*)&Vt[((size_t)b * HS + (c - 128)) * TT + tl0 + mi * 16 + lg * 4] = pk;
            }
        }
    }
}

// ================= Kernel B: per-batch causal flash attention, no barriers =================
__global__ __launch_bounds__(512, 4) void attn_fused(
    const ushort* __restrict__ Kg, const ushort* __restrict__ Qg,
    const ushort* __restrict__ Vt, float* __restrict__ out)
{
    const int b   = blockIdx.x;
    const int tid = threadIdx.x;
    const int l   = tid & 63;
    const int w   = tid >> 6;
    const int l15 = l & 15;
    const int lg  = l >> 4;

    __shared__ ushort pb[8][16 * 40];
    ushort* pbw = pb[w];

    const ushort* Kb = Kg + (size_t)b * TT * HS;
    const ushort* Qb = Qg + (size_t)b * TT * HS;
    const ushort* Vb = Vt + (size_t)b * HS * TT;

    #pragma unroll
    for (int half = 0; half < 2; ++half) {
        const int rt = half ? (15 - w) : w;     // balanced causal work: 9 chunks/wave
        const int t0 = rt * 16;

        short8_t afr[2];
        afr[0] = *(const short8_t*)&Kb[(t0 + l15) * HS + lg * 8];
        afr[1] = *(const short8_t*)&Kb[(t0 + l15) * HS + 32 + lg * 8];

        float mr[4], lr[4];
        f32x4 o[4];
        #pragma unroll
        for (int r = 0; r < 4; ++r) { mr[r] = -INFINITY; lr[r] = 0.f; }
        #pragma unroll
        for (int nt = 0; nt < 4; ++nt) o[nt] = (f32x4){0.f, 0.f, 0.f, 0.f};

        const int jd = t0 >> 5;
        for (int j = 0; j <= jd; ++j) {
            const int sb = j * 32;
            f32x4 sacc[2];
            sacc[0] = (f32x4){0.f, 0.f, 0.f, 0.f};
            sacc[1] = (f32x4){0.f, 0.f, 0.f, 0.f};
            #pragma unroll
            for (int kk = 0; kk < 2; ++kk) {
                #pragma unroll
                for (int ct = 0; ct < 2; ++ct) {
                    short8_t bfr = *(const short8_t*)&Qb[(sb + ct * 16 + l15) * HS + kk * 32 + lg * 8];
                    sacc[ct] = __builtin_amdgcn_mfma_f32_16x16x32_bf16(afr[kk], bfr, sacc[ct], 0, 0, 0);
                }
            }
            #pragma unroll
            for (int ct = 0; ct < 2; ++ct) {
                int s = sb + ct * 16 + l15;
                #pragma unroll
                for (int r = 0; r < 4; ++r) {
                    int t = t0 + lg * 4 + r;
                    if (s > t) sacc[ct][r] = -INFINITY;
                }
            }
            float p0[4], p1[4], fsc[4];
            #pragma unroll
            for (int r = 0; r < 4; ++r) {
                float mx = fmaxf(sacc[0][r], sacc[1][r]);
                mx = fmaxf(mx, __shfl_xor(mx, 1));
                mx = fmaxf(mx, __shfl_xor(mx, 2));
                mx = fmaxf(mx, __shfl_xor(mx, 4));
                mx = fmaxf(mx, __shfl_xor(mx, 8));
                float nm = fmaxf(mr[r], mx);
                fsc[r] = __expf(mr[r] - nm);
                mr[r] = nm;
                p0[r] = __expf(sacc[0][r] - nm);
                p1[r] = __expf(sacc[1][r] - nm);
                float ps = p0[r] + p1[r];
                ps += __shfl_xor(ps, 1);
                ps += __shfl_xor(ps, 2);
                ps += __shfl_xor(ps, 4);
                ps += __shfl_xor(ps, 8);
                lr[r] = lr[r] * fsc[r] + ps;
            }
            #pragma unroll
            for (int nt = 0; nt < 4; ++nt)
                #pragma unroll
                for (int r = 0; r < 4; ++r) o[nt][r] *= fsc[r];
            #pragma unroll
            for (int r = 0; r < 4; ++r) {
                pbw[(lg * 4 + r) * 40 + l15]      = f2bf(p0[r]);
                pbw[(lg * 4 + r) * 40 + 16 + l15] = f2bf(p1[r]);
            }
            short8_t pa = *(const short8_t*)&pbw[l15 * 40 + lg * 8];
            #pragma unroll
            for (int nt = 0; nt < 4; ++nt) {
                short8_t bfr = *(const short8_t*)&Vb[(nt * 16 + l15) * TT + sb + lg * 8];
                o[nt] = __builtin_amdgcn_mfma_f32_16x16x32_bf16(pa, bfr, o[nt], 0, 0, 0);
            }
        }
        #pragma unroll
        for (int r = 0; r < 4; ++r) {
            float inv = 1.0f / lr[r];
            int t = t0 + lg * 4 + r;
            float* op = out + ((size_t)b * TT + t) * HS;
            #pragma unroll
            for (int nt = 0; nt < 4; ++nt)
                op[nt * 16 + l15] = o[nt][r] * inv;
        }
    }
}

extern "C" void kernel_launch(void* const* d_in, const int* in_sizes, int n_in,
                              void* d_out, int out_size, void* d_ws, size_t ws_size,
                              hipStream_t stream) {
    const float* x  = (const float*)d_in[0];
    const float* Wk = (const float*)d_in[1];
    const float* bk = (const float*)d_in[2];
    const float* Wq = (const float*)d_in[3];
    const float* bq = (const float*)d_in[4];
    const float* Wv = (const float*)d_in[5];
    const float* bv = (const float*)d_in[6];
    float* out = (float*)d_out;

    ushort* WTr = (ushort*)d_ws;
    ushort* Kg  = (ushort*)((char*)d_ws + K_OFF_B);
    ushort* Qg  = (ushort*)((char*)d_ws + Q_OFF_B);
    ushort* Vt  = (ushort*)((char*)d_ws + VT_OFF_B);

    prep_wtr<<<dim3(144), dim3(64), 0, stream>>>(Wk, Wq, Wv, WTr);
    proj_gemm<<<dim3(2048), dim3(256), 0, stream>>>(x, WTr, bk, bq, bv, Kg, Qg, Vt);
    attn_fused<<<dim3(BB), dim3(512), 0, stream>>>(Kg, Qg, Vt, out);
}